// Round 1
// baseline (573.144 us; speedup 1.0000x reference)
//
#include <hip/hip_runtime.h>

typedef __attribute__((ext_vector_type(8))) short s16x8;
typedef __attribute__((ext_vector_type(4))) float fx4;
typedef __attribute__((ext_vector_type(4))) int ix4;

#define B_SZ 4
#define T_SZ 2048
#define DM 1024
#define NH 16
#define DK 64
#define M_SZ (B_SZ * T_SZ)   // 8192

__device__ __forceinline__ unsigned short f2bf(float f) {
    unsigned int u = __float_as_uint(f);
    unsigned int r = u + 0x7fffu + ((u >> 16) & 1u);
    return (unsigned short)(r >> 16);
}

__device__ __forceinline__ void async16(const unsigned short* g, unsigned short* l) {
    __builtin_amdgcn_global_load_lds(
        (const __attribute__((address_space(1))) unsigned int*)g,
        (__attribute__((address_space(3))) unsigned int*)l, 16, 0, 0);
}

// ---------------- cast fp32 -> bf16 (vectorized) ----------------
__global__ void cast_f32_bf16(const float* __restrict__ src, unsigned short* __restrict__ dst, int n) {
    int i = (blockIdx.x * blockDim.x + threadIdx.x) * 4;
    int stride = gridDim.x * blockDim.x * 4;
    for (; i + 3 < n; i += stride) {
        float4 v = *(const float4*)(src + i);
        ushort4 o;
        o.x = f2bf(v.x); o.y = f2bf(v.y); o.z = f2bf(v.z); o.w = f2bf(v.w);
        *(ushort4*)(dst + i) = o;
    }
}

// ---------------- GEMM: C[M][N] = A[M][K] * Bw[N][K]^T  (m97 structure) ----------------
// 128x128 tile, BK=32, 256 threads (4 waves, 2x2 of 64x64), 16x16x32 bf16 MFMA.
template<int OUT_BF16>
__global__ __launch_bounds__(256) void gemm_bt(const unsigned short* __restrict__ A,
                                               const unsigned short* __restrict__ Bw,
                                               void* __restrict__ Cout,
                                               int M, int N, int K, float scale) {
    __shared__ __align__(16) unsigned short As[128 * 32];
    __shared__ __align__(16) unsigned short Bs[128 * 32];

    const int t = threadIdx.x;
    const int lane = t & 63;
    const int w = t >> 6;
    const int wm = w >> 1, wn = w & 1;
    const int lrow = lane & 15, lk = lane >> 4;
    const int m0 = blockIdx.y * 128, n0 = blockIdx.x * 128;

    fx4 acc[4][4] = {};

    const int arow = t >> 2;           // 0..63 (two issues cover 128 rows)
    const int acol = (t & 3) * 8;      // k offset (elements)
    const unsigned short* Ag = A + (long)(m0 + arow) * K + acol;
    const unsigned short* Bg = Bw + (long)(n0 + arow) * K + acol;
    const int lds0 = t * 8;            // elements; = 16B per thread, linear

    for (int kt = 0; kt < K; kt += 32) {
        __syncthreads();
        async16(Ag + kt, &As[lds0]);
        async16(Ag + 64 * K + kt, &As[lds0 + 64 * 32]);
        async16(Bg + kt, &Bs[lds0]);
        async16(Bg + 64 * K + kt, &Bs[lds0 + 64 * 32]);
        __syncthreads();

        s16x8 af[4], bf[4];
#pragma unroll
        for (int i = 0; i < 4; ++i)
            af[i] = *(const s16x8*)&As[(wm * 64 + i * 16 + lrow) * 32 + lk * 8];
#pragma unroll
        for (int i = 0; i < 4; ++i)
            bf[i] = *(const s16x8*)&Bs[(wn * 64 + i * 16 + lrow) * 32 + lk * 8];
#pragma unroll
        for (int i = 0; i < 4; ++i)
#pragma unroll
            for (int j = 0; j < 4; ++j)
                acc[i][j] = __builtin_amdgcn_mfma_f32_16x16x32_bf16(af[i], bf[j], acc[i][j], 0, 0, 0);
    }

#pragma unroll
    for (int i = 0; i < 4; ++i)
#pragma unroll
        for (int j = 0; j < 4; ++j)
#pragma unroll
            for (int r = 0; r < 4; ++r) {
                int row = m0 + wm * 64 + i * 16 + lk * 4 + r;
                int col = n0 + wn * 64 + j * 16 + lrow;
                float v = acc[i][j][r] * scale;
                if (OUT_BF16)
                    ((unsigned short*)Cout)[(long)row * N + col] = f2bf(v);
                else
                    ((float*)Cout)[(long)row * N + col] = v;
            }
}

// ---------------- Flash attention (causal), bf16 MFMA ----------------
// Grid: (T/64, H, B). Block: 256 threads = 4 waves; wave w owns q rows [q0blk + 16w, +16).
// KV tile = 32. Q pre-scaled by 0.125*log2(e); softmax uses exp2.
__global__ __launch_bounds__(256) void attn_kernel(const unsigned short* __restrict__ Q,
                                                   const unsigned short* __restrict__ Kb,
                                                   const unsigned short* __restrict__ Vb,
                                                   unsigned short* __restrict__ O) {
    __shared__ __align__(16) unsigned short Ks[32][72];   // +8 pad: 2-way (free) conflicts
    __shared__ __align__(16) unsigned short VT[64][40];   // V transposed: [d][k], +8 pad
    __shared__ __align__(16) unsigned short Pl[4][16][40];// per-wave P tile 16x32, +8 pad

    const int t = threadIdx.x;
    const int w = t >> 6, lane = t & 63;
    const int lrow = lane & 15, lk = lane >> 4;
    const int qblk = blockIdx.x, h = blockIdx.y, b = blockIdx.z;
    const int row0 = b * T_SZ;
    const int q0 = qblk * 64 + w * 16;

    // Q fragments (2 d-chunks of 32)
    s16x8 qf[2];
    const unsigned short* Qrow = Q + (long)(row0 + q0 + lrow) * DM + h * DK;
#pragma unroll
    for (int c = 0; c < 2; ++c)
        qf[c] = *(const s16x8*)(Qrow + c * 32 + lk * 8);

    fx4 acc[4] = {};
    float mrow[4], lsum[4];
#pragma unroll
    for (int r = 0; r < 4; ++r) { mrow[r] = -__builtin_inff(); lsum[r] = 0.f; }

    const int nt = qblk * 2 + 2;          // KV tiles of 32 covering cols [0, q0blk+64)
    const int trow = t >> 3, tcol = (t & 7) * 8;

    for (int kt = 0; kt < nt; ++kt) {
        __syncthreads();
        // stage K tile [32][64] and V tile transposed [64][32]
        union { ix4 v; unsigned short u[8]; } kv, vv;
        kv.v = *(const ix4*)(Kb + (long)(row0 + kt * 32 + trow) * DM + h * DK + tcol);
        vv.v = *(const ix4*)(Vb + (long)(row0 + kt * 32 + trow) * DM + h * DK + tcol);
        *(ix4*)&Ks[trow][tcol] = kv.v;
#pragma unroll
        for (int j = 0; j < 8; ++j)
            VT[tcol + j][trow] = vv.u[j];
        __syncthreads();

        // S = Qs * K^T   (16 q-rows x 32 k-cols per wave)
        fx4 s[2] = {};
#pragma unroll
        for (int nf = 0; nf < 2; ++nf)
#pragma unroll
            for (int c = 0; c < 2; ++c)
                s[nf] = __builtin_amdgcn_mfma_f32_16x16x32_bf16(
                    qf[c], *(const s16x8*)&Ks[nf * 16 + lrow][c * 32 + lk * 8], s[nf], 0, 0, 0);

        // causal mask + online softmax (per-row stats across 16-lane groups)
        float p[2][4], sc[4];
#pragma unroll
        for (int r = 0; r < 4; ++r) {
            int qrow = q0 + lk * 4 + r;
#pragma unroll
            for (int nf = 0; nf < 2; ++nf) {
                int col = kt * 32 + nf * 16 + lrow;
                if (col > qrow) s[nf][r] = -__builtin_inff();
            }
            float rm = fmaxf(s[0][r], s[1][r]);
#pragma unroll
            for (int off = 1; off < 16; off <<= 1)
                rm = fmaxf(rm, __shfl_xor(rm, off));
            float newm = fmaxf(mrow[r], rm);
            sc[r] = exp2f(mrow[r] - newm);
            float rs = 0.f;
#pragma unroll
            for (int nf = 0; nf < 2; ++nf) {
                p[nf][r] = exp2f(s[nf][r] - newm);
                rs += p[nf][r];
            }
#pragma unroll
            for (int off = 1; off < 16; off <<= 1)
                rs += __shfl_xor(rs, off);
            lsum[r] = lsum[r] * sc[r] + rs;
            mrow[r] = newm;
        }
#pragma unroll
        for (int nf = 0; nf < 4; ++nf)
#pragma unroll
            for (int r = 0; r < 4; ++r)
                acc[nf][r] *= sc[r];

        // P -> LDS (bf16) to get the MFMA A-fragment layout
#pragma unroll
        for (int nf = 0; nf < 2; ++nf)
#pragma unroll
            for (int r = 0; r < 4; ++r)
                Pl[w][lk * 4 + r][nf * 16 + lrow] = f2bf(p[nf][r]);
        __syncthreads();

        // O += P * V
        s16x8 pf = *(const s16x8*)&Pl[w][lrow][lk * 8];
#pragma unroll
        for (int nf = 0; nf < 4; ++nf)
            acc[nf] = __builtin_amdgcn_mfma_f32_16x16x32_bf16(
                pf, *(const s16x8*)&VT[nf * 16 + lrow][lk * 8], acc[nf], 0, 0, 0);
    }

    // finalize: divide by row sum, write O
#pragma unroll
    for (int nf = 0; nf < 4; ++nf)
#pragma unroll
        for (int r = 0; r < 4; ++r) {
            int row = row0 + q0 + lk * 4 + r;
            int col = h * DK + nf * 16 + lrow;
            O[(long)row * DM + col] = f2bf(acc[nf][r] / lsum[r]);
        }
}

extern "C" void kernel_launch(void* const* d_in, const int* in_sizes, int n_in,
                              void* d_out, int out_size, void* d_ws, size_t ws_size,
                              hipStream_t stream) {
    const float* x  = (const float*)d_in[0];
    const float* Wq = (const float*)d_in[1];
    const float* Wk = (const float*)d_in[2];
    const float* Wv = (const float*)d_in[3];
    const float* Wo = (const float*)d_in[4];
    float* out = (float*)d_out;

    unsigned short* wsu = (unsigned short*)d_ws;
    unsigned short* xb  = wsu;                  // 8,388,608 elems
    unsigned short* wqb = xb + 8388608;         // 1,048,576
    unsigned short* wkb = wqb + 1048576;
    unsigned short* wvb = wkb + 1048576;
    unsigned short* wob = wvb + 1048576;
    unsigned short* Qs  = wob + 1048576;        // 8,388,608
    unsigned short* Ob  = Qs + 8388608;         // 8,388,608  (total ws: 58.7 MB)

    // K,V bf16 live in d_out's 32MB (read by attn, then overwritten by final GEMM)
    unsigned short* Kb = (unsigned short*)d_out;
    unsigned short* Vb = Kb + 8388608;

    // casts
    cast_f32_bf16<<<2048, 256, 0, stream>>>(x, xb, M_SZ * DM);
    cast_f32_bf16<<<1024, 256, 0, stream>>>(Wq, wqb, DM * DM);
    cast_f32_bf16<<<1024, 256, 0, stream>>>(Wk, wkb, DM * DM);
    cast_f32_bf16<<<1024, 256, 0, stream>>>(Wv, wvb, DM * DM);
    cast_f32_bf16<<<1024, 256, 0, stream>>>(Wo, wob, DM * DM);

    dim3 ggrid(DM / 128, M_SZ / 128);  // (8, 64)
    const float qscale = 0.125f * 1.44269504088896340736f;  // (1/sqrt(dk)) * log2(e)
    gemm_bt<1><<<ggrid, 256, 0, stream>>>(xb, wqb, Qs, M_SZ, DM, DM, qscale);
    gemm_bt<1><<<ggrid, 256, 0, stream>>>(xb, wkb, Kb, M_SZ, DM, DM, 1.f);
    gemm_bt<1><<<ggrid, 256, 0, stream>>>(xb, wvb, Vb, M_SZ, DM, DM, 1.f);

    dim3 agrid(T_SZ / 64, NH, B_SZ);   // (32, 16, 4)
    attn_kernel<<<agrid, 256, 0, stream>>>(Qs, Kb, Vb, Ob);

    gemm_bt<0><<<ggrid, 256, 0, stream>>>(Ob, wob, out, M_SZ, DM, DM, 1.f);
}

// Round 3
// 308.081 us; speedup vs baseline: 1.8604x; 1.8604x over previous
//
#include <hip/hip_runtime.h>

typedef __attribute__((ext_vector_type(8))) short s16x8;
typedef __attribute__((ext_vector_type(4))) float fx4;
typedef __attribute__((ext_vector_type(4))) int ix4;

#define B_SZ 4
#define T_SZ 2048
#define DM 1024
#define NH 16
#define DK 64
#define M_SZ (B_SZ * T_SZ)   // 8192
#define NINF (-__builtin_inff())

__device__ __forceinline__ unsigned short f2bf(float f) {
    unsigned int u = __float_as_uint(f);
    unsigned int r = u + 0x7fffu + ((u >> 16) & 1u);
    return (unsigned short)(r >> 16);
}

__device__ __forceinline__ void async16(const unsigned short* g, unsigned short* l) {
    __builtin_amdgcn_global_load_lds(
        (const __attribute__((address_space(1))) unsigned int*)g,
        (__attribute__((address_space(3))) unsigned int*)l, 16, 0, 0);
}

// ---------------- cast fp32 -> bf16 (vectorized) ----------------
__global__ void cast_f32_bf16(const float* __restrict__ src, unsigned short* __restrict__ dst, int n) {
    int i = (blockIdx.x * blockDim.x + threadIdx.x) * 4;
    int stride = gridDim.x * blockDim.x * 4;
    for (; i + 3 < n; i += stride) {
        float4 v = *(const float4*)(src + i);
        ushort4 o;
        o.x = f2bf(v.x); o.y = f2bf(v.y); o.z = f2bf(v.z); o.w = f2bf(v.w);
        *(ushort4*)(dst + i) = o;
    }
}

// ---------------- GEMM: C[M][N] = A[M][K] * Bw[N][K]^T  (m97 structure, verified R1) ----------------
template<int OUT_BF16>
__global__ __launch_bounds__(256) void gemm_bt(const unsigned short* __restrict__ A,
                                               const unsigned short* __restrict__ Bw,
                                               void* __restrict__ Cout,
                                               int M, int N, int K, float scale) {
    __shared__ __align__(16) unsigned short As[128 * 32];
    __shared__ __align__(16) unsigned short Bs[128 * 32];

    const int t = threadIdx.x;
    const int lane = t & 63;
    const int w = t >> 6;
    const int wm = w >> 1, wn = w & 1;
    const int lrow = lane & 15, lk = lane >> 4;
    const int m0 = blockIdx.y * 128, n0 = blockIdx.x * 128;

    fx4 acc[4][4] = {};

    const int arow = t >> 2;
    const int acol = (t & 3) * 8;
    const unsigned short* Ag = A + (long)(m0 + arow) * K + acol;
    const unsigned short* Bg = Bw + (long)(n0 + arow) * K + acol;
    const int lds0 = t * 8;

    for (int kt = 0; kt < K; kt += 32) {
        __syncthreads();
        async16(Ag + kt, &As[lds0]);
        async16(Ag + 64 * K + kt, &As[lds0 + 64 * 32]);
        async16(Bg + kt, &Bs[lds0]);
        async16(Bg + 64 * K + kt, &Bs[lds0 + 64 * 32]);
        __syncthreads();

        s16x8 af[4], bf[4];
#pragma unroll
        for (int i = 0; i < 4; ++i)
            af[i] = *(const s16x8*)&As[(wm * 64 + i * 16 + lrow) * 32 + lk * 8];
#pragma unroll
        for (int i = 0; i < 4; ++i)
            bf[i] = *(const s16x8*)&Bs[(wn * 64 + i * 16 + lrow) * 32 + lk * 8];
#pragma unroll
        for (int i = 0; i < 4; ++i)
#pragma unroll
            for (int j = 0; j < 4; ++j)
                acc[i][j] = __builtin_amdgcn_mfma_f32_16x16x32_bf16(af[i], bf[j], acc[i][j], 0, 0, 0);
    }

#pragma unroll
    for (int i = 0; i < 4; ++i)
#pragma unroll
        for (int j = 0; j < 4; ++j)
#pragma unroll
            for (int r = 0; r < 4; ++r) {
                int row = m0 + wm * 64 + i * 16 + lk * 4 + r;
                int col = n0 + wn * 64 + j * 16 + lrow;
                float v = acc[i][j][r] * scale;
                if (OUT_BF16)
                    ((unsigned short*)Cout)[(long)row * N + col] = f2bf(v);
                else
                    ((float*)Cout)[(long)row * N + col] = v;
            }
}

// ---------------- Flash attention: swapped-S^T, 16x16x32 MFMA only ----------------
// Grid: (16, NH, B). Block: 512 threads = 8 waves; wave w owns q rows [qb*128 + 16w, +16).
// KV tile 64, double-buffered. K: async16 + chunk-XOR source pre-swizzle.
// V: reg-staged, transposed into VT with slot swizzle (write banks free, read uniform).
// S^T = K·Q^T via mfma(A=Kfrag, B=Qfrag): output col = lane&15 = own q -> per-lane softmax.
__global__ __launch_bounds__(512, 2) void attn_kernel(const unsigned short* __restrict__ Q,
                                                      const unsigned short* __restrict__ Kb,
                                                      const unsigned short* __restrict__ Vb,
                                                      unsigned short* __restrict__ O) {
    __shared__ __align__(16) unsigned short Ks[2][64 * 64];   // linear, async16 dest
    __shared__ __align__(16) unsigned short VT[2][64 * 72];   // VT[d][kv] slot-swizzled
    __shared__ __align__(16) unsigned short Pl[8][16 * 72];   // per-wave P, stride 72

    const int t = threadIdx.x;
    const int lane = t & 63, w = t >> 6;
    const int lrow = lane & 15, lk = lane >> 4;
    const int qb = 15 - blockIdx.x;                 // heavy blocks dispatch first
    const int h = blockIdx.y, b = blockIdx.z;
    const int row0 = b * T_SZ;
    const int q0w = qb * 128 + w * 16;

    // Q fragments: lane holds Q[q0w+lrow][c*32 + lk*8 .. +8]  (same per-lane data as R1)
    s16x8 qf[2];
    {
        const unsigned short* qp = Q + (long)(row0 + q0w + lrow) * DM + h * DK + lk * 8;
#pragma unroll
        for (int c = 0; c < 2; ++c) qf[c] = *(const s16x8*)(qp + c * 32);
    }

    fx4 acc[4] = {};
    float mrun = NINF, lsum = 0.f;

    // staging addresses
    const int srow = t >> 3;                               // 0..63 (kv row)
    const int kchunk = (t & 7) ^ (srow & 7);               // K source pre-swizzle
    const unsigned short* Kg = Kb + (long)(row0 + srow) * DM + h * DK + kchunk * 8;
    const unsigned short* Vg = Vb + (long)(row0 + srow) * DM + h * DK + (t & 7) * 8;
    unsigned short* Kl = &Ks[0][t * 8];
    // VT write: element (d=(t&7)*8+j, kv=srow) -> d*72 + 8*((kv>>3)^(d>>3)) + (kv&7)
    const int vtswz = 8 * ((t >> 6) ^ (t & 7)) + (srow & 7);

    const int nt = 2 * qb + 2;

    // prologue: stage tile 0 into buffer 0
    async16(Kg, Kl);
    {
        union { ix4 v; unsigned short u[8]; } uu;
        uu.v = *(const ix4*)Vg;
#pragma unroll
        for (int j = 0; j < 8; ++j)
            VT[0][((t & 7) * 8 + j) * 72 + vtswz] = uu.u[j];
    }
    asm volatile("s_waitcnt vmcnt(0)" ::: "memory");
    __syncthreads();

    for (int kt = 0; kt < nt; ++kt) {
        const int cur = kt & 1;
        const bool pre = (kt + 1 < nt);
        ix4 vreg2 = {};
        if (pre) {
            const long off = (long)(kt + 1) * 64 * DM;
            async16(Kg + off, Kl + (cur ^ 1) * 4096);
            vreg2 = *(const ix4*)(Vg + off);
        }
        const int kv0 = kt * 64;
        if (kv0 <= q0w + 15) {
            const char* ksb = (const char*)&Ks[cur][0];
            float p[4][4];
            float pm = NINF;
            // ---- S^T = K·Q^T, causal mask, collect row stats ----
#pragma unroll
            for (int sub = 0; sub < 4; ++sub) {
                const int kv0s = kv0 + sub * 16;
                if (kv0s <= q0w + 15) {
                    fx4 s = {};
#pragma unroll
                    for (int c = 0; c < 2; ++c) {
                        const s16x8 kf = *(const s16x8*)(ksb + (((sub * 16 + lrow) << 7) +
                                            ((c * 64 + lk * 16) ^ ((lrow & 7) << 4))));
                        s = __builtin_amdgcn_mfma_f32_16x16x32_bf16(kf, qf[c], s, 0, 0, 0);
                    }
                    if (kv0s + 15 > q0w) {
#pragma unroll
                        for (int r = 0; r < 4; ++r)
                            if (kv0s + lk * 4 + r > q0w + lrow) s[r] = NINF;
                    }
#pragma unroll
                    for (int r = 0; r < 4; ++r) { p[sub][r] = s[r]; pm = fmaxf(pm, s[r]); }
                } else {
#pragma unroll
                    for (int r = 0; r < 4; ++r) p[sub][r] = NINF;
                }
            }
            // ---- online softmax (q = lrow; row spread over lanes l, l^16, l^32, l^48) ----
            pm = fmaxf(pm, __shfl_xor(pm, 16));
            pm = fmaxf(pm, __shfl_xor(pm, 32));
            const float mnew = fmaxf(mrun, pm);
            const float sc = exp2f(mrun - mnew);
            mrun = mnew;
            float ps = 0.f;
#pragma unroll
            for (int sub = 0; sub < 4; ++sub)
#pragma unroll
                for (int r = 0; r < 4; ++r) {
                    const float pv = exp2f(p[sub][r] - mnew);
                    p[sub][r] = pv;
                    ps += pv;
                }
            ps += __shfl_xor(ps, 16);
            ps += __shfl_xor(ps, 32);
            lsum = lsum * sc + ps;
#pragma unroll
            for (int r = 0; r < 4; ++r) {
                const float scr = __shfl(sc, lk * 4 + r);
                acc[0][r] *= scr; acc[1][r] *= scr; acc[2][r] *= scr; acc[3][r] *= scr;
            }
            // ---- P -> per-wave LDS (bf16 pairs) ----
#pragma unroll
            for (int sub = 0; sub < 4; ++sub) {
                if (kv0 + (sub >> 1) * 32 <= q0w + 15) {
                    const unsigned w0 = (unsigned)f2bf(p[sub][0]) | ((unsigned)f2bf(p[sub][1]) << 16);
                    const unsigned w1 = (unsigned)f2bf(p[sub][2]) | ((unsigned)f2bf(p[sub][3]) << 16);
                    *(unsigned*)&Pl[w][lrow * 72 + sub * 16 + lk * 4]     = w0;
                    *(unsigned*)&Pl[w][lrow * 72 + sub * 16 + lk * 4 + 2] = w1;
                }
            }
            // ---- O += P·V ----
#pragma unroll
            for (int s = 0; s < 2; ++s) {
                if (kv0 + s * 32 <= q0w + 15) {
                    const s16x8 pf = *(const s16x8*)&Pl[w][lrow * 72 + s * 32 + lk * 8];
#pragma unroll
                    for (int nf = 0; nf < 4; ++nf) {
                        const int d = nf * 16 + lrow;
                        const s16x8 vf = *(const s16x8*)&VT[cur][d * 72 + (((s * 4 + lk) ^ (d >> 3)) << 3)];
                        acc[nf] = __builtin_amdgcn_mfma_f32_16x16x32_bf16(pf, vf, acc[nf], 0, 0, 0);
                    }
                }
            }
        }
        // write next V tile (reads of VT[cur^1] finished before this iteration's start)
        if (pre) {
            union { ix4 v; unsigned short u[8]; } uu;
            uu.v = vreg2;
#pragma unroll
            for (int j = 0; j < 8; ++j)
                VT[cur ^ 1][((t & 7) * 8 + j) * 72 + vtswz] = uu.u[j];
        }
        asm volatile("s_waitcnt vmcnt(0)" ::: "memory");
        __syncthreads();
    }

    // ---- epilogue ----
    float linv[4];
#pragma unroll
    for (int r = 0; r < 4; ++r) linv[r] = 1.f / __shfl(lsum, lk * 4 + r);
    unsigned short* op = O + (long)(row0 + q0w) * DM + h * DK;
#pragma unroll
    for (int nf = 0; nf < 4; ++nf)
#pragma unroll
        for (int r = 0; r < 4; ++r)
            op[(long)(lk * 4 + r) * DM + nf * 16 + lrow] = f2bf(acc[nf][r] * linv[r]);
}

extern "C" void kernel_launch(void* const* d_in, const int* in_sizes, int n_in,
                              void* d_out, int out_size, void* d_ws, size_t ws_size,
                              hipStream_t stream) {
    const float* x  = (const float*)d_in[0];
    const float* Wq = (const float*)d_in[1];
    const float* Wk = (const float*)d_in[2];
    const float* Wv = (const float*)d_in[3];
    const float* Wo = (const float*)d_in[4];
    float* out = (float*)d_out;

    unsigned short* wsu = (unsigned short*)d_ws;
    unsigned short* xb  = wsu;                  // 8,388,608 elems
    unsigned short* wqb = xb + 8388608;         // 1,048,576
    unsigned short* wkb = wqb + 1048576;
    unsigned short* wvb = wkb + 1048576;
    unsigned short* wob = wvb + 1048576;
    unsigned short* Qs  = wob + 1048576;        // 8,388,608
    unsigned short* Ob  = Qs + 8388608;         // 8,388,608

    // K,V bf16 live in d_out's 32MB (read by attn, then overwritten by final GEMM)
    unsigned short* Kb = (unsigned short*)d_out;
    unsigned short* Vb = Kb + 8388608;

    cast_f32_bf16<<<2048, 256, 0, stream>>>(x, xb, M_SZ * DM);
    cast_f32_bf16<<<1024, 256, 0, stream>>>(Wq, wqb, DM * DM);
    cast_f32_bf16<<<1024, 256, 0, stream>>>(Wk, wkb, DM * DM);
    cast_f32_bf16<<<1024, 256, 0, stream>>>(Wv, wvb, DM * DM);
    cast_f32_bf16<<<1024, 256, 0, stream>>>(Wo, wob, DM * DM);

    dim3 ggrid(DM / 128, M_SZ / 128);  // (8, 64)
    const float qscale = 0.125f * 1.44269504088896340736f;  // (1/sqrt(dk)) * log2(e)
    gemm_bt<1><<<ggrid, 256, 0, stream>>>(xb, wqb, Qs, M_SZ, DM, DM, qscale);
    gemm_bt<1><<<ggrid, 256, 0, stream>>>(xb, wkb, Kb, M_SZ, DM, DM, 1.f);
    gemm_bt<1><<<ggrid, 256, 0, stream>>>(xb, wvb, Vb, M_SZ, DM, DM, 1.f);

    dim3 agrid(16, NH, B_SZ);          // 1024 blocks, heavy-first
    attn_kernel<<<agrid, 512, 0, stream>>>(Qs, Kb, Vb, Ob);

    gemm_bt<0><<<ggrid, 256, 0, stream>>>(Ob, wob, out, M_SZ, DM, DM, 1.f);
}

// Round 4
// 296.283 us; speedup vs baseline: 1.9344x; 1.0398x over previous
//
#include <hip/hip_runtime.h>

typedef __attribute__((ext_vector_type(8))) short s16x8;
typedef __attribute__((ext_vector_type(4))) float fx4;
typedef __attribute__((ext_vector_type(4))) int ix4;

#define B_SZ 4
#define T_SZ 2048
#define DM 1024
#define NH 16
#define DK 64
#define M_SZ (B_SZ * T_SZ)   // 8192
#define NINF (-__builtin_inff())

__device__ __forceinline__ unsigned short f2bf(float f) {
    unsigned int u = __float_as_uint(f);
    unsigned int r = u + 0x7fffu + ((u >> 16) & 1u);
    return (unsigned short)(r >> 16);
}

__device__ __forceinline__ void async16(const unsigned short* g, unsigned short* l) {
    __builtin_amdgcn_global_load_lds(
        (const __attribute__((address_space(1))) unsigned int*)g,
        (__attribute__((address_space(3))) unsigned int*)l, 16, 0, 0);
}

// ---------------- cast fp32 -> bf16 (vectorized) ----------------
__global__ void cast_f32_bf16(const float* __restrict__ src, unsigned short* __restrict__ dst, int n) {
    int i = (blockIdx.x * blockDim.x + threadIdx.x) * 4;
    int stride = gridDim.x * blockDim.x * 4;
    for (; i + 3 < n; i += stride) {
        float4 v = *(const float4*)(src + i);
        ushort4 o;
        o.x = f2bf(v.x); o.y = f2bf(v.y); o.z = f2bf(v.z); o.w = f2bf(v.w);
        *(ushort4*)(dst + i) = o;
    }
}

// fused cast of the 4 weight matrices (dsts contiguous at dst + y*1M)
__global__ void cast_w4(const float* __restrict__ s0, const float* __restrict__ s1,
                        const float* __restrict__ s2, const float* __restrict__ s3,
                        unsigned short* __restrict__ dst) {
    const float* s = (blockIdx.y == 0) ? s0 : (blockIdx.y == 1) ? s1 : (blockIdx.y == 2) ? s2 : s3;
    unsigned short* d = dst + (size_t)blockIdx.y * (DM * DM);
    int i = (blockIdx.x * blockDim.x + threadIdx.x) * 4;
    int stride = gridDim.x * blockDim.x * 4;
    for (; i + 3 < DM * DM; i += stride) {
        float4 v = *(const float4*)(s + i);
        ushort4 o;
        o.x = f2bf(v.x); o.y = f2bf(v.y); o.z = f2bf(v.z); o.w = f2bf(v.w);
        *(ushort4*)(d + i) = o;
    }
}

// ---------------- GEMM: C[M][N] = A[M][K] * Bw[N][K]^T ----------------
// m97 fragment structure + 2-phase double-buffer with counted vmcnt(4):
// stage(next) -> vmcnt(4) -> barrier -> compute(cur) -> barrier.
template<int OUT_BF16>
__global__ __launch_bounds__(256) void gemm_bt(const unsigned short* __restrict__ A,
                                               const unsigned short* __restrict__ Bw,
                                               void* __restrict__ Cout,
                                               int M, int N, int K, float scale) {
    __shared__ __align__(16) unsigned short As[2][128 * 32];
    __shared__ __align__(16) unsigned short Bs[2][128 * 32];

    const int t = threadIdx.x;
    const int lane = t & 63;
    const int w = t >> 6;
    const int wm = w >> 1, wn = w & 1;
    const int lrow = lane & 15, lk = lane >> 4;
    const int m0 = blockIdx.y * 128, n0 = blockIdx.x * 128;

    fx4 acc[4][4] = {};

    const int arow = t >> 2;
    const int acol = (t & 3) * 8;
    const unsigned short* Ag = A + (long)(m0 + arow) * K + acol;
    const unsigned short* Bg = Bw + (long)(n0 + arow) * K + acol;
    const int lds0 = t * 8;
    const int nk = K / 32;

    // prologue: stage tile 0 -> buf 0
    async16(Ag, &As[0][lds0]);
    async16(Ag + 64 * K, &As[0][lds0 + 64 * 32]);
    async16(Bg, &Bs[0][lds0]);
    async16(Bg + 64 * K, &Bs[0][lds0 + 64 * 32]);

    for (int kt = 0; kt < nk; ++kt) {
        const int cur = kt & 1;
        if (kt + 1 < nk) {
            const int ko = (kt + 1) * 32;
            async16(Ag + ko, &As[cur ^ 1][lds0]);
            async16(Ag + 64 * K + ko, &As[cur ^ 1][lds0 + 64 * 32]);
            async16(Bg + ko, &Bs[cur ^ 1][lds0]);
            async16(Bg + 64 * K + ko, &Bs[cur ^ 1][lds0 + 64 * 32]);
            asm volatile("s_waitcnt vmcnt(4)" ::: "memory");   // wait only tile kt's loads
        } else {
            asm volatile("s_waitcnt vmcnt(0)" ::: "memory");
        }
        __syncthreads();

        s16x8 af[4], bf[4];
#pragma unroll
        for (int i = 0; i < 4; ++i)
            af[i] = *(const s16x8*)&As[cur][(wm * 64 + i * 16 + lrow) * 32 + lk * 8];
#pragma unroll
        for (int i = 0; i < 4; ++i)
            bf[i] = *(const s16x8*)&Bs[cur][(wn * 64 + i * 16 + lrow) * 32 + lk * 8];
#pragma unroll
        for (int i = 0; i < 4; ++i)
#pragma unroll
            for (int j = 0; j < 4; ++j)
                acc[i][j] = __builtin_amdgcn_mfma_f32_16x16x32_bf16(af[i], bf[j], acc[i][j], 0, 0, 0);
        __syncthreads();   // reads of buf[cur] done before next iter overwrites it
    }

#pragma unroll
    for (int i = 0; i < 4; ++i)
#pragma unroll
        for (int j = 0; j < 4; ++j)
#pragma unroll
            for (int r = 0; r < 4; ++r) {
                int row = m0 + wm * 64 + i * 16 + lk * 4 + r;
                int col = n0 + wn * 64 + j * 16 + lrow;
                float v = acc[i][j][r] * scale;
                if (OUT_BF16)
                    ((unsigned short*)Cout)[(long)row * N + col] = f2bf(v);
                else
                    ((float*)Cout)[(long)row * N + col] = v;
            }
}

// ---------------- Flash attention: swapped-S^T, 16x16x32 MFMA, defer-max ----------------
__global__ __launch_bounds__(512, 2) void attn_kernel(const unsigned short* __restrict__ Q,
                                                      const unsigned short* __restrict__ Kb,
                                                      const unsigned short* __restrict__ Vb,
                                                      unsigned short* __restrict__ O) {
    __shared__ __align__(16) unsigned short Ks[2][64 * 64];   // linear, async16 dest
    __shared__ __align__(16) unsigned short VT[2][64 * 72];   // VT[d][kv] slot-swizzled
    __shared__ __align__(16) unsigned short Pl[8][16 * 72];   // per-wave P, stride 72

    const int t = threadIdx.x;
    const int lane = t & 63, w = t >> 6;
    const int lrow = lane & 15, lk = lane >> 4;
    const int qb = 15 - blockIdx.x;                 // heavy blocks dispatch first
    const int h = blockIdx.y, b = blockIdx.z;
    const int row0 = b * T_SZ;
    const int q0w = qb * 128 + w * 16;

    s16x8 qf[2];
    {
        const unsigned short* qp = Q + (long)(row0 + q0w + lrow) * DM + h * DK + lk * 8;
#pragma unroll
        for (int c = 0; c < 2; ++c) qf[c] = *(const s16x8*)(qp + c * 32);
    }

    fx4 acc[4] = {};
    float mrun = NINF, lsum = 0.f;

    const int srow = t >> 3;
    const int kchunk = (t & 7) ^ (srow & 7);
    const unsigned short* Kg = Kb + (long)(row0 + srow) * DM + h * DK + kchunk * 8;
    const unsigned short* Vg = Vb + (long)(row0 + srow) * DM + h * DK + (t & 7) * 8;
    unsigned short* Kl = &Ks[0][t * 8];
    const int vtswz = 8 * ((t >> 6) ^ (t & 7)) + (srow & 7);

    const int nt = 2 * qb + 2;

    // prologue: stage tile 0 into buffer 0
    async16(Kg, Kl);
    {
        union { ix4 v; unsigned short u[8]; } uu;
        uu.v = *(const ix4*)Vg;
#pragma unroll
        for (int j = 0; j < 8; ++j)
            VT[0][((t & 7) * 8 + j) * 72 + vtswz] = uu.u[j];
    }
    asm volatile("s_waitcnt vmcnt(0)" ::: "memory");
    __syncthreads();

    for (int kt = 0; kt < nt; ++kt) {
        const int cur = kt & 1;
        const bool pre = (kt + 1 < nt);
        ix4 vreg2 = {};
        if (pre) {
            const long off = (long)(kt + 1) * 64 * DM;
            async16(Kg + off, Kl + (cur ^ 1) * 4096);
            vreg2 = *(const ix4*)(Vg + off);
        }
        const int kv0 = kt * 64;
        if (kv0 <= q0w + 15) {
            const char* ksb = (const char*)&Ks[cur][0];
            float p[4][4];
            float pm = NINF;
#pragma unroll
            for (int sub = 0; sub < 4; ++sub) {
                const int kv0s = kv0 + sub * 16;
                if (kv0s <= q0w + 15) {
                    fx4 s = {};
#pragma unroll
                    for (int c = 0; c < 2; ++c) {
                        const s16x8 kf = *(const s16x8*)(ksb + (((sub * 16 + lrow) << 7) +
                                            ((c * 64 + lk * 16) ^ ((lrow & 7) << 4))));
                        s = __builtin_amdgcn_mfma_f32_16x16x32_bf16(kf, qf[c], s, 0, 0, 0);
                    }
                    if (kv0s + 15 > q0w) {
#pragma unroll
                        for (int r = 0; r < 4; ++r)
                            if (kv0s + lk * 4 + r > q0w + lrow) s[r] = NINF;
                    }
#pragma unroll
                    for (int r = 0; r < 4; ++r) { p[sub][r] = s[r]; pm = fmaxf(pm, s[r]); }
                } else {
#pragma unroll
                    for (int r = 0; r < 4; ++r) p[sub][r] = NINF;
                }
            }
            // ---- online softmax with defer-max (THR=8 in exp2 domain) ----
            pm = fmaxf(pm, __shfl_xor(pm, 16));
            pm = fmaxf(pm, __shfl_xor(pm, 32));
            if (__any(pm > mrun + 8.f)) {            // rescale fires rarely
                const float mnew = fmaxf(mrun, pm);
                const float sc = exp2f(mrun - mnew);
                mrun = mnew;
                lsum *= sc;
#pragma unroll
                for (int r = 0; r < 4; ++r) {
                    const float scr = __shfl(sc, lk * 4 + r);
                    acc[0][r] *= scr; acc[1][r] *= scr; acc[2][r] *= scr; acc[3][r] *= scr;
                }
            }
            float ps = 0.f;
#pragma unroll
            for (int sub = 0; sub < 4; ++sub)
#pragma unroll
                for (int r = 0; r < 4; ++r) {
                    const float pv = exp2f(p[sub][r] - mrun);
                    p[sub][r] = pv;
                    ps += pv;
                }
            ps += __shfl_xor(ps, 16);
            ps += __shfl_xor(ps, 32);
            lsum += ps;
            // ---- P -> per-wave LDS (b64 writes) ----
#pragma unroll
            for (int sub = 0; sub < 4; ++sub) {
                if (kv0 + (sub >> 1) * 32 <= q0w + 15) {
                    uint2 pw;
                    pw.x = (unsigned)f2bf(p[sub][0]) | ((unsigned)f2bf(p[sub][1]) << 16);
                    pw.y = (unsigned)f2bf(p[sub][2]) | ((unsigned)f2bf(p[sub][3]) << 16);
                    *(uint2*)&Pl[w][lrow * 72 + sub * 16 + lk * 4] = pw;
                }
            }
            // ---- O += P·V ----
#pragma unroll
            for (int s = 0; s < 2; ++s) {
                if (kv0 + s * 32 <= q0w + 15) {
                    const s16x8 pf = *(const s16x8*)&Pl[w][lrow * 72 + s * 32 + lk * 8];
#pragma unroll
                    for (int nf = 0; nf < 4; ++nf) {
                        const int d = nf * 16 + lrow;
                        const s16x8 vf = *(const s16x8*)&VT[cur][d * 72 + (((s * 4 + lk) ^ (d >> 3)) << 3)];
                        acc[nf] = __builtin_amdgcn_mfma_f32_16x16x32_bf16(pf, vf, acc[nf], 0, 0, 0);
                    }
                }
            }
        }
        if (pre) {
            union { ix4 v; unsigned short u[8]; } uu;
            uu.v = vreg2;
#pragma unroll
            for (int j = 0; j < 8; ++j)
                VT[cur ^ 1][((t & 7) * 8 + j) * 72 + vtswz] = uu.u[j];
        }
        asm volatile("s_waitcnt vmcnt(0)" ::: "memory");
        __syncthreads();
    }

    float linv[4];
#pragma unroll
    for (int r = 0; r < 4; ++r) linv[r] = 1.f / __shfl(lsum, lk * 4 + r);
    unsigned short* op = O + (long)(row0 + q0w) * DM + h * DK;
#pragma unroll
    for (int nf = 0; nf < 4; ++nf)
#pragma unroll
        for (int r = 0; r < 4; ++r)
            op[(long)(lk * 4 + r) * DM + nf * 16 + lrow] = f2bf(acc[nf][r] * linv[r]);
}

extern "C" void kernel_launch(void* const* d_in, const int* in_sizes, int n_in,
                              void* d_out, int out_size, void* d_ws, size_t ws_size,
                              hipStream_t stream) {
    const float* x  = (const float*)d_in[0];
    const float* Wq = (const float*)d_in[1];
    const float* Wk = (const float*)d_in[2];
    const float* Wv = (const float*)d_in[3];
    const float* Wo = (const float*)d_in[4];
    float* out = (float*)d_out;

    unsigned short* wsu = (unsigned short*)d_ws;
    unsigned short* xb  = wsu;                  // 8,388,608 elems
    unsigned short* wqb = xb + 8388608;         // 4 x 1,048,576 (contiguous)
    unsigned short* wkb = wqb + 1048576;
    unsigned short* wvb = wkb + 1048576;
    unsigned short* wob = wvb + 1048576;
    unsigned short* Qs  = wob + 1048576;        // 8,388,608
    unsigned short* Ob  = Qs + 8388608;         // 8,388,608

    unsigned short* Kb = (unsigned short*)d_out;
    unsigned short* Vb = Kb + 8388608;

    cast_f32_bf16<<<2048, 256, 0, stream>>>(x, xb, M_SZ * DM);
    cast_w4<<<dim3(256, 4), 256, 0, stream>>>(Wq, Wk, Wv, Wo, wqb);

    dim3 ggrid(DM / 128, M_SZ / 128);  // (8, 64)
    const float qscale = 0.125f * 1.44269504088896340736f;  // (1/sqrt(dk)) * log2(e)
    gemm_bt<1><<<ggrid, 256, 0, stream>>>(xb, wqb, Qs, M_SZ, DM, DM, qscale);
    gemm_bt<1><<<ggrid, 256, 0, stream>>>(xb, wkb, Kb, M_SZ, DM, DM, 1.f);
    gemm_bt<1><<<ggrid, 256, 0, stream>>>(xb, wvb, Vb, M_SZ, DM, DM, 1.f);

    dim3 agrid(16, NH, B_SZ);          // 1024 blocks, heavy-first
    attn_kernel<<<agrid, 512, 0, stream>>>(Qs, Kb, Vb, Ob);

    gemm_bt<0><<<ggrid, 256, 0, stream>>>(Ob, wob, out, M_SZ, DM, DM, 1.f);
}

// Round 5
// 289.124 us; speedup vs baseline: 1.9823x; 1.0248x over previous
//
#include <hip/hip_runtime.h>

typedef __attribute__((ext_vector_type(8))) short s16x8;
typedef __attribute__((ext_vector_type(4))) float fx4;
typedef __attribute__((ext_vector_type(4))) int ix4;

#define B_SZ 4
#define T_SZ 2048
#define DM 1024
#define NH 16
#define DK 64
#define M_SZ (B_SZ * T_SZ)   // 8192
#define NINF (-__builtin_inff())

__device__ __forceinline__ unsigned short f2bf(float f) {
    unsigned int u = __float_as_uint(f);
    unsigned int r = u + 0x7fffu + ((u >> 16) & 1u);
    return (unsigned short)(r >> 16);
}

__device__ __forceinline__ unsigned cvtpk(float lo, float hi) {
    unsigned r;
    asm("v_cvt_pk_bf16_f32 %0, %1, %2" : "=v"(r) : "v"(lo), "v"(hi));
    return r;
}

__device__ __forceinline__ void async16(const unsigned short* g, unsigned short* l) {
    __builtin_amdgcn_global_load_lds(
        (const __attribute__((address_space(1))) unsigned int*)g,
        (__attribute__((address_space(3))) unsigned int*)l, 16, 0, 0);
}

// ---------------- cast fp32 -> bf16 (vectorized) ----------------
__global__ void cast_f32_bf16(const float* __restrict__ src, unsigned short* __restrict__ dst, int n) {
    int i = (blockIdx.x * blockDim.x + threadIdx.x) * 4;
    int stride = gridDim.x * blockDim.x * 4;
    for (; i + 3 < n; i += stride) {
        float4 v = *(const float4*)(src + i);
        ushort4 o;
        o.x = f2bf(v.x); o.y = f2bf(v.y); o.z = f2bf(v.z); o.w = f2bf(v.w);
        *(ushort4*)(dst + i) = o;
    }
}

// fused cast of the 4 weight matrices (dsts contiguous at dst + y*1M)
__global__ void cast_w4(const float* __restrict__ s0, const float* __restrict__ s1,
                        const float* __restrict__ s2, const float* __restrict__ s3,
                        unsigned short* __restrict__ dst) {
    const float* s = (blockIdx.y == 0) ? s0 : (blockIdx.y == 1) ? s1 : (blockIdx.y == 2) ? s2 : s3;
    unsigned short* d = dst + (size_t)blockIdx.y * (DM * DM);
    int i = (blockIdx.x * blockDim.x + threadIdx.x) * 4;
    int stride = gridDim.x * blockDim.x * 4;
    for (; i + 3 < DM * DM; i += stride) {
        float4 v = *(const float4*)(s + i);
        ushort4 o;
        o.x = f2bf(v.x); o.y = f2bf(v.y); o.z = f2bf(v.z); o.w = f2bf(v.w);
        *(ushort4*)(d + i) = o;
    }
}

// ---------------- GEMM: C[M][N] = A[M][K] * Bw[N][K]^T ----------------
// m97 fragment structure + 2-phase double-buffer with counted vmcnt(4).
template<int OUT_BF16>
__global__ __launch_bounds__(256) void gemm_bt(const unsigned short* __restrict__ A,
                                               const unsigned short* __restrict__ Bw,
                                               void* __restrict__ Cout,
                                               int M, int N, int K, float scale) {
    __shared__ __align__(16) unsigned short As[2][128 * 32];
    __shared__ __align__(16) unsigned short Bs[2][128 * 32];

    const int t = threadIdx.x;
    const int lane = t & 63;
    const int w = t >> 6;
    const int wm = w >> 1, wn = w & 1;
    const int lrow = lane & 15, lk = lane >> 4;
    const int m0 = blockIdx.y * 128, n0 = blockIdx.x * 128;

    fx4 acc[4][4] = {};

    const int arow = t >> 2;
    const int acol = (t & 3) * 8;
    const unsigned short* Ag = A + (long)(m0 + arow) * K + acol;
    const unsigned short* Bg = Bw + (long)(n0 + arow) * K + acol;
    const int lds0 = t * 8;
    const int nk = K / 32;

    async16(Ag, &As[0][lds0]);
    async16(Ag + 64 * K, &As[0][lds0 + 64 * 32]);
    async16(Bg, &Bs[0][lds0]);
    async16(Bg + 64 * K, &Bs[0][lds0 + 64 * 32]);

    for (int kt = 0; kt < nk; ++kt) {
        const int cur = kt & 1;
        if (kt + 1 < nk) {
            const int ko = (kt + 1) * 32;
            async16(Ag + ko, &As[cur ^ 1][lds0]);
            async16(Ag + 64 * K + ko, &As[cur ^ 1][lds0 + 64 * 32]);
            async16(Bg + ko, &Bs[cur ^ 1][lds0]);
            async16(Bg + 64 * K + ko, &Bs[cur ^ 1][lds0 + 64 * 32]);
            asm volatile("s_waitcnt vmcnt(4)" ::: "memory");
        } else {
            asm volatile("s_waitcnt vmcnt(0)" ::: "memory");
        }
        __syncthreads();

        s16x8 af[4], bf[4];
#pragma unroll
        for (int i = 0; i < 4; ++i)
            af[i] = *(const s16x8*)&As[cur][(wm * 64 + i * 16 + lrow) * 32 + lk * 8];
#pragma unroll
        for (int i = 0; i < 4; ++i)
            bf[i] = *(const s16x8*)&Bs[cur][(wn * 64 + i * 16 + lrow) * 32 + lk * 8];
#pragma unroll
        for (int i = 0; i < 4; ++i)
#pragma unroll
            for (int j = 0; j < 4; ++j)
                acc[i][j] = __builtin_amdgcn_mfma_f32_16x16x32_bf16(af[i], bf[j], acc[i][j], 0, 0, 0);
        __syncthreads();
    }

#pragma unroll
    for (int i = 0; i < 4; ++i)
#pragma unroll
        for (int j = 0; j < 4; ++j)
#pragma unroll
            for (int r = 0; r < 4; ++r) {
                int row = m0 + wm * 64 + i * 16 + lk * 4 + r;
                int col = n0 + wn * 64 + j * 16 + lrow;
                float v = acc[i][j][r] * scale;
                if (OUT_BF16)
                    ((unsigned short*)Cout)[(long)row * N + col] = f2bf(v);
                else
                    ((float*)Cout)[(long)row * N + col] = v;
            }
}

// ---------------- Flash attention: swapped-S^T, 32 q-rows/wave (2 halves), frag reuse ----------------
// Grid: (8, NH, B). Block: 512 threads = 8 waves; wave w owns q rows [qb*256 + 32w, +32).
// KV tile 64, double-buffered. kf/vf LDS fragments read ONCE, used by both q-halves.
__global__ __launch_bounds__(512, 4) void attn_kernel(const unsigned short* __restrict__ Q,
                                                      const unsigned short* __restrict__ Kb,
                                                      const unsigned short* __restrict__ Vb,
                                                      unsigned short* __restrict__ O) {
    __shared__ __align__(16) unsigned short Ks[2][64 * 64];   // linear, async16 dest
    __shared__ __align__(16) unsigned short VT[2][64 * 72];   // VT[d][kv] slot-swizzled
    __shared__ __align__(16) unsigned short Pl[8][16 * 72];   // per-wave P, reused by halves

    const int t = threadIdx.x;
    const int lane = t & 63, w = t >> 6;
    const int lrow = lane & 15, lk = lane >> 4;
    const int qb = 7 - blockIdx.x;                 // heavy blocks dispatch first
    const int h = blockIdx.y, b = blockIdx.z;
    const int row0 = b * T_SZ;
    const int q0w = qb * 256 + w * 32;

    s16x8 qf[2][2];
#pragma unroll
    for (int hh = 0; hh < 2; ++hh) {
        const unsigned short* qp = Q + (long)(row0 + q0w + hh * 16 + lrow) * DM + h * DK + lk * 8;
        qf[hh][0] = *(const s16x8*)qp;
        qf[hh][1] = *(const s16x8*)(qp + 32);
    }

    fx4 acc[2][4] = {};
    float mrun[2] = {NINF, NINF}, lsum[2] = {0.f, 0.f};

    const int srow = t >> 3;
    const int kchunk = (t & 7) ^ (srow & 7);
    const unsigned short* Kg = Kb + (long)(row0 + srow) * DM + h * DK + kchunk * 8;
    const unsigned short* Vg = Vb + (long)(row0 + srow) * DM + h * DK + (t & 7) * 8;
    unsigned short* Kl = &Ks[0][t * 8];
    const int vtswz = 8 * ((t >> 6) ^ (t & 7)) + (srow & 7);

    const int nt = 4 * qb + 4;

    // prologue: stage tile 0 into buffer 0
    async16(Kg, Kl);
    {
        union { ix4 v; unsigned short u[8]; } uu;
        uu.v = *(const ix4*)Vg;
#pragma unroll
        for (int j = 0; j < 8; ++j)
            VT[0][((t & 7) * 8 + j) * 72 + vtswz] = uu.u[j];
    }
    asm volatile("s_waitcnt vmcnt(0)" ::: "memory");
    __syncthreads();

    for (int kt = 0; kt < nt; ++kt) {
        const int cur = kt & 1;
        const bool pre = (kt + 1 < nt);
        ix4 vreg2 = {};
        if (pre) {
            const long off = (long)(kt + 1) * 64 * DM;
            async16(Kg + off, Kl + (cur ^ 1) * 4096);
            vreg2 = *(const ix4*)(Vg + off);
        }
        const int kv0 = kt * 64;
        if (kv0 <= q0w + 31) {
            const char* ksb = (const char*)&Ks[cur][0];
            float p[2][4][4];
            float pm0 = NINF, pm1 = NINF;
            // ---- S^T = K·Q^T for both halves with kf reuse ----
#pragma unroll
            for (int sub = 0; sub < 4; ++sub) {
                const int kv0s = kv0 + sub * 16;
                if (kv0s <= q0w + 31) {          // half 1 active
                    const int rb = (sub * 16 + lrow) << 7;
                    const int sw = (lrow & 7) << 4;
                    const s16x8 kf0 = *(const s16x8*)(ksb + (rb + ((lk * 16) ^ sw)));
                    const s16x8 kf1 = *(const s16x8*)(ksb + (rb + ((64 + lk * 16) ^ sw)));
                    fx4 s1 = {};
                    s1 = __builtin_amdgcn_mfma_f32_16x16x32_bf16(kf0, qf[1][0], s1, 0, 0, 0);
                    s1 = __builtin_amdgcn_mfma_f32_16x16x32_bf16(kf1, qf[1][1], s1, 0, 0, 0);
                    if (kv0s + 15 > q0w + 16) {
#pragma unroll
                        for (int r = 0; r < 4; ++r)
                            if (kv0s + lk * 4 + r > q0w + 16 + lrow) s1[r] = NINF;
                    }
#pragma unroll
                    for (int r = 0; r < 4; ++r) { p[1][sub][r] = s1[r]; pm1 = fmaxf(pm1, s1[r]); }
                    if (kv0s <= q0w + 15) {      // half 0 active
                        fx4 s0 = {};
                        s0 = __builtin_amdgcn_mfma_f32_16x16x32_bf16(kf0, qf[0][0], s0, 0, 0, 0);
                        s0 = __builtin_amdgcn_mfma_f32_16x16x32_bf16(kf1, qf[0][1], s0, 0, 0, 0);
                        if (kv0s + 15 > q0w) {
#pragma unroll
                            for (int r = 0; r < 4; ++r)
                                if (kv0s + lk * 4 + r > q0w + lrow) s0[r] = NINF;
                        }
#pragma unroll
                        for (int r = 0; r < 4; ++r) { p[0][sub][r] = s0[r]; pm0 = fmaxf(pm0, s0[r]); }
                    } else {
#pragma unroll
                        for (int r = 0; r < 4; ++r) p[0][sub][r] = NINF;
                    }
                } else {
#pragma unroll
                    for (int r = 0; r < 4; ++r) { p[0][sub][r] = NINF; p[1][sub][r] = NINF; }
                }
            }
            // ---- online softmax per half (defer-max THR=8) ----
            float pmv[2] = {pm0, pm1};
#pragma unroll
            for (int hh = 0; hh < 2; ++hh) {
                float pm = pmv[hh];
                pm = fmaxf(pm, __shfl_xor(pm, 16));
                pm = fmaxf(pm, __shfl_xor(pm, 32));
                if (__any(pm > mrun[hh] + 8.f)) {
                    const float mnew = fmaxf(mrun[hh], pm);
                    const float sc = exp2f(mrun[hh] - mnew);
                    mrun[hh] = mnew;
                    lsum[hh] *= sc;
#pragma unroll
                    for (int r = 0; r < 4; ++r) {
                        const float scr = __shfl(sc, lk * 4 + r);
                        acc[hh][0][r] *= scr; acc[hh][1][r] *= scr;
                        acc[hh][2][r] *= scr; acc[hh][3][r] *= scr;
                    }
                }
                float ps = 0.f;
#pragma unroll
                for (int sub = 0; sub < 4; ++sub)
#pragma unroll
                    for (int r = 0; r < 4; ++r) {
                        const float pv = exp2f(p[hh][sub][r] - mrun[hh]);
                        p[hh][sub][r] = pv;
                        ps += pv;
                    }
                ps += __shfl_xor(ps, 16);
                ps += __shfl_xor(ps, 32);
                lsum[hh] += ps;
            }
            // ---- pack P per half through per-wave LDS (cvt_pk; sequential reuse) ----
            s16x8 pf[2][2];
#pragma unroll
            for (int hh = 0; hh < 2; ++hh) {
#pragma unroll
                for (int sub = 0; sub < 4; ++sub) {
                    uint2 pw;
                    pw.x = cvtpk(p[hh][sub][0], p[hh][sub][1]);
                    pw.y = cvtpk(p[hh][sub][2], p[hh][sub][3]);
                    *(uint2*)&Pl[w][lrow * 72 + sub * 16 + lk * 4] = pw;
                }
                pf[hh][0] = *(const s16x8*)&Pl[w][lrow * 72 + lk * 8];
                pf[hh][1] = *(const s16x8*)&Pl[w][lrow * 72 + 32 + lk * 8];
            }
            // ---- O += P·V with vf reuse across halves ----
#pragma unroll
            for (int s = 0; s < 2; ++s) {
                if (kv0 + s * 32 <= q0w + 31) {
                    const bool h0a = (kv0 + s * 32 <= q0w + 15);
#pragma unroll
                    for (int nf = 0; nf < 4; ++nf) {
                        const int d = nf * 16 + lrow;
                        const s16x8 vf = *(const s16x8*)&VT[cur][d * 72 + (((s * 4 + lk) ^ (d >> 3)) << 3)];
                        if (h0a)
                            acc[0][nf] = __builtin_amdgcn_mfma_f32_16x16x32_bf16(pf[0][s], vf, acc[0][nf], 0, 0, 0);
                        acc[1][nf] = __builtin_amdgcn_mfma_f32_16x16x32_bf16(pf[1][s], vf, acc[1][nf], 0, 0, 0);
                    }
                }
            }
        }
        // write next V tile
        if (pre) {
            union { ix4 v; unsigned short u[8]; } uu;
            uu.v = vreg2;
#pragma unroll
            for (int j = 0; j < 8; ++j)
                VT[cur ^ 1][((t & 7) * 8 + j) * 72 + vtswz] = uu.u[j];
        }
        asm volatile("s_waitcnt vmcnt(0)" ::: "memory");
        __syncthreads();
    }

    // ---- epilogue ----
#pragma unroll
    for (int hh = 0; hh < 2; ++hh) {
        float linv[4];
#pragma unroll
        for (int r = 0; r < 4; ++r) linv[r] = 1.f / __shfl(lsum[hh], lk * 4 + r);
        unsigned short* op = O + (long)(row0 + q0w + hh * 16) * DM + h * DK;
#pragma unroll
        for (int nf = 0; nf < 4; ++nf)
#pragma unroll
            for (int r = 0; r < 4; ++r)
                op[(long)(lk * 4 + r) * DM + nf * 16 + lrow] = f2bf(acc[hh][nf][r] * linv[r]);
    }
}

extern "C" void kernel_launch(void* const* d_in, const int* in_sizes, int n_in,
                              void* d_out, int out_size, void* d_ws, size_t ws_size,
                              hipStream_t stream) {
    const float* x  = (const float*)d_in[0];
    const float* Wq = (const float*)d_in[1];
    const float* Wk = (const float*)d_in[2];
    const float* Wv = (const float*)d_in[3];
    const float* Wo = (const float*)d_in[4];
    float* out = (float*)d_out;

    unsigned short* wsu = (unsigned short*)d_ws;
    unsigned short* xb  = wsu;                  // 8,388,608 elems
    unsigned short* wqb = xb + 8388608;         // 4 x 1,048,576 (contiguous)
    unsigned short* wkb = wqb + 1048576;
    unsigned short* wvb = wkb + 1048576;
    unsigned short* wob = wvb + 1048576;
    unsigned short* Qs  = wob + 1048576;        // 8,388,608
    unsigned short* Ob  = Qs + 8388608;         // 8,388,608

    unsigned short* Kb = (unsigned short*)d_out;
    unsigned short* Vb = Kb + 8388608;

    cast_f32_bf16<<<2048, 256, 0, stream>>>(x, xb, M_SZ * DM);
    cast_w4<<<dim3(256, 4), 256, 0, stream>>>(Wq, Wk, Wv, Wo, wqb);

    dim3 ggrid(DM / 128, M_SZ / 128);  // (8, 64)
    const float qscale = 0.125f * 1.44269504088896340736f;  // (1/sqrt(dk)) * log2(e)
    gemm_bt<1><<<ggrid, 256, 0, stream>>>(xb, wqb, Qs, M_SZ, DM, DM, qscale);
    gemm_bt<1><<<ggrid, 256, 0, stream>>>(xb, wkb, Kb, M_SZ, DM, DM, 1.f);
    gemm_bt<1><<<ggrid, 256, 0, stream>>>(xb, wvb, Vb, M_SZ, DM, DM, 1.f);

    dim3 agrid(8, NH, B_SZ);           // 512 blocks, heavy-first
    attn_kernel<<<agrid, 512, 0, stream>>>(Qs, Kb, Vb, Ob);

    gemm_bt<0><<<ggrid, 256, 0, stream>>>(Ob, wob, out, M_SZ, DM, DM, 1.f);
}

// Round 6
// 235.655 us; speedup vs baseline: 2.4321x; 1.2269x over previous
//
#include <hip/hip_runtime.h>

typedef __attribute__((ext_vector_type(8))) short s16x8;
typedef __attribute__((ext_vector_type(4))) float fx4;
typedef __attribute__((ext_vector_type(4))) int ix4;

#define B_SZ 4
#define T_SZ 2048
#define DM 1024
#define NH 16
#define DK 64
#define M_SZ (B_SZ * T_SZ)   // 8192
#define NINF (-__builtin_inff())

__device__ __forceinline__ unsigned short f2bf(float f) {
    unsigned int u = __float_as_uint(f);
    unsigned int r = u + 0x7fffu + ((u >> 16) & 1u);
    return (unsigned short)(r >> 16);
}

__device__ __forceinline__ unsigned cvtpk(float lo, float hi) {
    unsigned r;
    asm("v_cvt_pk_bf16_f32 %0, %1, %2" : "=v"(r) : "v"(lo), "v"(hi));
    return r;
}

__device__ __forceinline__ void async16(const unsigned short* g, unsigned short* l) {
    __builtin_amdgcn_global_load_lds(
        (const __attribute__((address_space(1))) unsigned int*)g,
        (__attribute__((address_space(3))) unsigned int*)l, 16, 0, 0);
}

// ---------------- cast fp32 -> bf16 (vectorized) ----------------
__global__ void cast_f32_bf16(const float* __restrict__ src, unsigned short* __restrict__ dst, int n) {
    int i = (blockIdx.x * blockDim.x + threadIdx.x) * 4;
    int stride = gridDim.x * blockDim.x * 4;
    for (; i + 3 < n; i += stride) {
        float4 v = *(const float4*)(src + i);
        ushort4 o;
        o.x = f2bf(v.x); o.y = f2bf(v.y); o.z = f2bf(v.z); o.w = f2bf(v.w);
        *(ushort4*)(dst + i) = o;
    }
}

// fused cast of the 4 weight matrices (dsts contiguous at dst + y*1M)
__global__ void cast_w4(const float* __restrict__ s0, const float* __restrict__ s1,
                        const float* __restrict__ s2, const float* __restrict__ s3,
                        unsigned short* __restrict__ dst) {
    const float* s = (blockIdx.y == 0) ? s0 : (blockIdx.y == 1) ? s1 : (blockIdx.y == 2) ? s2 : s3;
    unsigned short* d = dst + (size_t)blockIdx.y * (DM * DM);
    int i = (blockIdx.x * blockDim.x + threadIdx.x) * 4;
    int stride = gridDim.x * blockDim.x * 4;
    for (; i + 3 < DM * DM; i += stride) {
        float4 v = *(const float4*)(s + i);
        ushort4 o;
        o.x = f2bf(v.x); o.y = f2bf(v.y); o.z = f2bf(v.z); o.w = f2bf(v.w);
        *(ushort4*)(d + i) = o;
    }
}

// ---------------- GEMM: C[M][N] = A[M][K] * Bw[N][K]^T ----------------
// m97 fragment structure + 2-phase double-buffer with counted vmcnt(4).
template<int OUT_BF16>
__global__ __launch_bounds__(256) void gemm_bt(const unsigned short* __restrict__ A,
                                               const unsigned short* __restrict__ Bw,
                                               void* __restrict__ Cout,
                                               int M, int N, int K, float scale) {
    __shared__ __align__(16) unsigned short As[2][128 * 32];
    __shared__ __align__(16) unsigned short Bs[2][128 * 32];

    const int t = threadIdx.x;
    const int lane = t & 63;
    const int w = t >> 6;
    const int wm = w >> 1, wn = w & 1;
    const int lrow = lane & 15, lk = lane >> 4;
    const int m0 = blockIdx.y * 128, n0 = blockIdx.x * 128;

    fx4 acc[4][4] = {};

    const int arow = t >> 2;
    const int acol = (t & 3) * 8;
    const unsigned short* Ag = A + (long)(m0 + arow) * K + acol;
    const unsigned short* Bg = Bw + (long)(n0 + arow) * K + acol;
    const int lds0 = t * 8;
    const int nk = K / 32;

    async16(Ag, &As[0][lds0]);
    async16(Ag + 64 * K, &As[0][lds0 + 64 * 32]);
    async16(Bg, &Bs[0][lds0]);
    async16(Bg + 64 * K, &Bs[0][lds0 + 64 * 32]);

    for (int kt = 0; kt < nk; ++kt) {
        const int cur = kt & 1;
        if (kt + 1 < nk) {
            const int ko = (kt + 1) * 32;
            async16(Ag + ko, &As[cur ^ 1][lds0]);
            async16(Ag + 64 * K + ko, &As[cur ^ 1][lds0 + 64 * 32]);
            async16(Bg + ko, &Bs[cur ^ 1][lds0]);
            async16(Bg + 64 * K + ko, &Bs[cur ^ 1][lds0 + 64 * 32]);
            asm volatile("s_waitcnt vmcnt(4)" ::: "memory");
        } else {
            asm volatile("s_waitcnt vmcnt(0)" ::: "memory");
        }
        __syncthreads();

        s16x8 af[4], bf[4];
#pragma unroll
        for (int i = 0; i < 4; ++i)
            af[i] = *(const s16x8*)&As[cur][(wm * 64 + i * 16 + lrow) * 32 + lk * 8];
#pragma unroll
        for (int i = 0; i < 4; ++i)
            bf[i] = *(const s16x8*)&Bs[cur][(wn * 64 + i * 16 + lrow) * 32 + lk * 8];
#pragma unroll
        for (int i = 0; i < 4; ++i)
#pragma unroll
            for (int j = 0; j < 4; ++j)
                acc[i][j] = __builtin_amdgcn_mfma_f32_16x16x32_bf16(af[i], bf[j], acc[i][j], 0, 0, 0);
        __syncthreads();
    }

#pragma unroll
    for (int i = 0; i < 4; ++i)
#pragma unroll
        for (int j = 0; j < 4; ++j)
#pragma unroll
            for (int r = 0; r < 4; ++r) {
                int row = m0 + wm * 64 + i * 16 + lk * 4 + r;
                int col = n0 + wn * 64 + j * 16 + lrow;
                float v = acc[i][j][r] * scale;
                if (OUT_BF16)
                    ((unsigned short*)Cout)[(long)row * N + col] = f2bf(v);
                else
                    ((float*)Cout)[(long)row * N + col] = v;
            }
}

// ---------------- Flash attention: swapped-S^T, 4 waves x 32 q-rows, XCD-local grid ----------------
// Grid: (64=hb, 16=qb'). Block: 256 threads = 4 waves; wave w owns q rows [qb*128 + 32w, +32).
// linear bid % 8 == hb % 8  ->  all qb-blocks of one (b,h) on the SAME XCD (K/V L2-resident).
// qb = 15 - blockIdx.y  ->  heavy blocks dispatch first (balance via 1024 blocks, ~3 resident/CU).
__global__ __launch_bounds__(256, 4) void attn_kernel(const unsigned short* __restrict__ Q,
                                                      const unsigned short* __restrict__ Kb,
                                                      const unsigned short* __restrict__ Vb,
                                                      unsigned short* __restrict__ O) {
    __shared__ __align__(16) unsigned short Ks[2][64 * 64];   // linear, async16 dest
    __shared__ __align__(16) unsigned short VT[2][64 * 72];   // VT[d][kv] slot-swizzled
    __shared__ __align__(16) unsigned short Pl[4][16 * 72];   // per-wave P, reused by halves

    const int t = threadIdx.x;
    const int lane = t & 63, w = t >> 6;
    const int lrow = lane & 15, lk = lane >> 4;
    const int hb = blockIdx.x;
    const int h = hb & 15, b = hb >> 4;
    const int qb = 15 - blockIdx.y;                // heavy blocks dispatch first
    const int row0 = b * T_SZ;
    const int q0w = qb * 128 + w * 32;

    s16x8 qf[2][2];
#pragma unroll
    for (int hh = 0; hh < 2; ++hh) {
        const unsigned short* qp = Q + (long)(row0 + q0w + hh * 16 + lrow) * DM + h * DK + lk * 8;
        qf[hh][0] = *(const s16x8*)qp;
        qf[hh][1] = *(const s16x8*)(qp + 32);
    }

    fx4 acc[2][4] = {};
    float mrun[2] = {NINF, NINF}, lsum[2] = {0.f, 0.f};

    // staging: 256 threads cover 32 kv rows per issue; 2 issues per 64-row tile
    const int srow = t >> 3;                               // 0..31
    const int kchunk0 = (t & 7) ^ (srow & 7);              // K source pre-swizzle (row-dependent)
    const unsigned short* Kg = Kb + (long)(row0 + srow) * DM + h * DK + kchunk0 * 8;
    const unsigned short* Vg = Vb + (long)(row0 + srow) * DM + h * DK + (t & 7) * 8;
    unsigned short* Kl = &Ks[0][t * 8];
    // VT write slot for element (d=(t&7)*8+j, kv): d*72 + 8*((kv>>3)^(d>>3)) + (kv&7)
    const int vtswz0 = 8 * ((t >> 6) ^ (t & 7)) + (srow & 7);        // kv = srow
    const int vtswz1 = 8 * (((t >> 6) + 4) ^ (t & 7)) + (srow & 7);  // kv = srow+32

    const int nt = 2 * qb + 2;

    // prologue: stage tile 0 into buffer 0
    async16(Kg, Kl);
    async16(Kg + 32 * DM, Kl + 2048);
    {
        union { ix4 v; unsigned short u[8]; } ua, ub;
        ua.v = *(const ix4*)Vg;
        ub.v = *(const ix4*)(Vg + 32 * DM);
#pragma unroll
        for (int j = 0; j < 8; ++j) {
            VT[0][((t & 7) * 8 + j) * 72 + vtswz0] = ua.u[j];
            VT[0][((t & 7) * 8 + j) * 72 + vtswz1] = ub.u[j];
        }
    }
    asm volatile("s_waitcnt vmcnt(0)" ::: "memory");
    __syncthreads();

    for (int kt = 0; kt < nt; ++kt) {
        const int cur = kt & 1;
        const bool pre = (kt + 1 < nt);
        ix4 vreg2a = {}, vreg2b = {};
        if (pre) {
            const long off = (long)(kt + 1) * 64 * DM;
            async16(Kg + off, Kl + (cur ^ 1) * 4096);
            async16(Kg + off + 32 * DM, Kl + (cur ^ 1) * 4096 + 2048);
            vreg2a = *(const ix4*)(Vg + off);
            vreg2b = *(const ix4*)(Vg + off + 32 * DM);
        }
        const int kv0 = kt * 64;
        if (kv0 <= q0w + 31) {
            const char* ksb = (const char*)&Ks[cur][0];
            float p[2][4][4];
            float pm0 = NINF, pm1 = NINF;
            // ---- S^T = K·Q^T for both halves with kf reuse ----
#pragma unroll
            for (int sub = 0; sub < 4; ++sub) {
                const int kv0s = kv0 + sub * 16;
                if (kv0s <= q0w + 31) {          // half 1 active
                    const int rb = (sub * 16 + lrow) << 7;
                    const int sw = (lrow & 7) << 4;
                    const s16x8 kf0 = *(const s16x8*)(ksb + (rb + ((lk * 16) ^ sw)));
                    const s16x8 kf1 = *(const s16x8*)(ksb + (rb + ((64 + lk * 16) ^ sw)));
                    fx4 s1 = {};
                    s1 = __builtin_amdgcn_mfma_f32_16x16x32_bf16(kf0, qf[1][0], s1, 0, 0, 0);
                    s1 = __builtin_amdgcn_mfma_f32_16x16x32_bf16(kf1, qf[1][1], s1, 0, 0, 0);
                    if (kv0s + 15 > q0w + 16) {
#pragma unroll
                        for (int r = 0; r < 4; ++r)
                            if (kv0s + lk * 4 + r > q0w + 16 + lrow) s1[r] = NINF;
                    }
#pragma unroll
                    for (int r = 0; r < 4; ++r) { p[1][sub][r] = s1[r]; pm1 = fmaxf(pm1, s1[r]); }
                    if (kv0s <= q0w + 15) {      // half 0 active
                        fx4 s0 = {};
                        s0 = __builtin_amdgcn_mfma_f32_16x16x32_bf16(kf0, qf[0][0], s0, 0, 0, 0);
                        s0 = __builtin_amdgcn_mfma_f32_16x16x32_bf16(kf1, qf[0][1], s0, 0, 0, 0);
                        if (kv0s + 15 > q0w) {
#pragma unroll
                            for (int r = 0; r < 4; ++r)
                                if (kv0s + lk * 4 + r > q0w + lrow) s0[r] = NINF;
                        }
#pragma unroll
                        for (int r = 0; r < 4; ++r) { p[0][sub][r] = s0[r]; pm0 = fmaxf(pm0, s0[r]); }
                    } else {
#pragma unroll
                        for (int r = 0; r < 4; ++r) p[0][sub][r] = NINF;
                    }
                } else {
#pragma unroll
                    for (int r = 0; r < 4; ++r) { p[0][sub][r] = NINF; p[1][sub][r] = NINF; }
                }
            }
            // ---- online softmax per half (defer-max THR=8) ----
            float pmv[2] = {pm0, pm1};
#pragma unroll
            for (int hh = 0; hh < 2; ++hh) {
                float pm = pmv[hh];
                pm = fmaxf(pm, __shfl_xor(pm, 16));
                pm = fmaxf(pm, __shfl_xor(pm, 32));
                if (__any(pm > mrun[hh] + 8.f)) {
                    const float mnew = fmaxf(mrun[hh], pm);
                    const float sc = exp2f(mrun[hh] - mnew);
                    mrun[hh] = mnew;
                    lsum[hh] *= sc;
#pragma unroll
                    for (int r = 0; r < 4; ++r) {
                        const float scr = __shfl(sc, lk * 4 + r);
                        acc[hh][0][r] *= scr; acc[hh][1][r] *= scr;
                        acc[hh][2][r] *= scr; acc[hh][3][r] *= scr;
                    }
                }
                float ps = 0.f;
#pragma unroll
                for (int sub = 0; sub < 4; ++sub)
#pragma unroll
                    for (int r = 0; r < 4; ++r) {
                        const float pv = exp2f(p[hh][sub][r] - mrun[hh]);
                        p[hh][sub][r] = pv;
                        ps += pv;
                    }
                ps += __shfl_xor(ps, 16);
                ps += __shfl_xor(ps, 32);
                lsum[hh] += ps;
            }
            // ---- pack P per half through per-wave LDS (cvt_pk; sequential reuse) ----
            s16x8 pf[2][2];
#pragma unroll
            for (int hh = 0; hh < 2; ++hh) {
#pragma unroll
                for (int sub = 0; sub < 4; ++sub) {
                    uint2 pw;
                    pw.x = cvtpk(p[hh][sub][0], p[hh][sub][1]);
                    pw.y = cvtpk(p[hh][sub][2], p[hh][sub][3]);
                    *(uint2*)&Pl[w][lrow * 72 + sub * 16 + lk * 4] = pw;
                }
                pf[hh][0] = *(const s16x8*)&Pl[w][lrow * 72 + lk * 8];
                pf[hh][1] = *(const s16x8*)&Pl[w][lrow * 72 + 32 + lk * 8];
            }
            // ---- O += P·V with vf reuse across halves ----
#pragma unroll
            for (int s = 0; s < 2; ++s) {
                if (kv0 + s * 32 <= q0w + 31) {
                    const bool h0a = (kv0 + s * 32 <= q0w + 15);
#pragma unroll
                    for (int nf = 0; nf < 4; ++nf) {
                        const int d = nf * 16 + lrow;
                        const s16x8 vf = *(const s16x8*)&VT[cur][d * 72 + (((s * 4 + lk) ^ (d >> 3)) << 3)];
                        if (h0a)
                            acc[0][nf] = __builtin_amdgcn_mfma_f32_16x16x32_bf16(pf[0][s], vf, acc[0][nf], 0, 0, 0);
                        acc[1][nf] = __builtin_amdgcn_mfma_f32_16x16x32_bf16(pf[1][s], vf, acc[1][nf], 0, 0, 0);
                    }
                }
            }
        }
        // write next V tile
        if (pre) {
            union { ix4 v; unsigned short u[8]; } ua, ub;
            ua.v = vreg2a;
            ub.v = vreg2b;
#pragma unroll
            for (int j = 0; j < 8; ++j) {
                VT[cur ^ 1][((t & 7) * 8 + j) * 72 + vtswz0] = ua.u[j];
                VT[cur ^ 1][((t & 7) * 8 + j) * 72 + vtswz1] = ub.u[j];
            }
        }
        asm volatile("s_waitcnt vmcnt(0)" ::: "memory");
        __syncthreads();
    }

    // ---- epilogue ----
#pragma unroll
    for (int hh = 0; hh < 2; ++hh) {
        float linv[4];
#pragma unroll
        for (int r = 0; r < 4; ++r) linv[r] = 1.f / __shfl(lsum[hh], lk * 4 + r);
        unsigned short* op = O + (long)(row0 + q0w + hh * 16) * DM + h * DK;
#pragma unroll
        for (int nf = 0; nf < 4; ++nf)
#pragma unroll
            for (int r = 0; r < 4; ++r)
                op[(long)(lk * 4 + r) * DM + nf * 16 + lrow] = f2bf(acc[hh][nf][r] * linv[r]);
    }
}

extern "C" void kernel_launch(void* const* d_in, const int* in_sizes, int n_in,
                              void* d_out, int out_size, void* d_ws, size_t ws_size,
                              hipStream_t stream) {
    const float* x  = (const float*)d_in[0];
    const float* Wq = (const float*)d_in[1];
    const float* Wk = (const float*)d_in[2];
    const float* Wv = (const float*)d_in[3];
    const float* Wo = (const float*)d_in[4];
    float* out = (float*)d_out;

    unsigned short* wsu = (unsigned short*)d_ws;
    unsigned short* xb  = wsu;                  // 8,388,608 elems
    unsigned short* wqb = xb + 8388608;         // 4 x 1,048,576 (contiguous)
    unsigned short* wkb = wqb + 1048576;
    unsigned short* wvb = wkb + 1048576;
    unsigned short* wob = wvb + 1048576;
    unsigned short* Qs  = wob + 1048576;        // 8,388,608
    unsigned short* Ob  = Qs + 8388608;         // 8,388,608

    unsigned short* Kb = (unsigned short*)d_out;
    unsigned short* Vb = Kb + 8388608;

    cast_f32_bf16<<<2048, 256, 0, stream>>>(x, xb, M_SZ * DM);
    cast_w4<<<dim3(256, 4), 256, 0, stream>>>(Wq, Wk, Wv, Wo, wqb);

    dim3 ggrid(DM / 128, M_SZ / 128);  // (8, 64)
    const float qscale = 0.125f * 1.44269504088896340736f;  // (1/sqrt(dk)) * log2(e)
    gemm_bt<1><<<ggrid, 256, 0, stream>>>(xb, wqb, Qs, M_SZ, DM, DM, qscale);
    gemm_bt<1><<<ggrid, 256, 0, stream>>>(xb, wkb, Kb, M_SZ, DM, DM, 1.f);
    gemm_bt<1><<<ggrid, 256, 0, stream>>>(xb, wvb, Vb, M_SZ, DM, DM, 1.f);

    dim3 agrid(64, 16);                // x = (b,h) -> fixed XCD; y -> qb (heavy first)
    attn_kernel<<<agrid, 256, 0, stream>>>(Qs, Kb, Vb, Ob);

    gemm_bt<0><<<ggrid, 256, 0, stream>>>(Ob, wob, out, M_SZ, DM, DM, 1.f);
}